// Round 12
// baseline (15047.891 us; speedup 1.0000x reference)
//
#include <hip/hip_runtime.h>

typedef unsigned short u16;

#define T_STEPS 16
#define NREAL   3328
#define NVIRT   64
#define NTOT    3392
#define HIDD    384
#define FFD     1536
#define NSPARSE 256
#define NDENSE  3072
#define ROWS_ALL (T_STEPS*NTOT)   /* 54272 */
#define NHEAD   8
#define ATT_SCALE 0.14433756729740643f
#define IDSEG   (1<<30)
#define MIDCAP  27136
#define NG      1696
#define QKVLD   1152

using bf16x8 = __attribute__((ext_vector_type(8))) short;
using f32x4  = __attribute__((ext_vector_type(4))) float;

// ---------------- device helpers ----------------
__device__ __forceinline__ u16 f2b(float f){
  unsigned u = __float_as_uint(f);
  return (u16)((u + 0x7fffu + ((u>>16)&1u)) >> 16);
}
__device__ __forceinline__ void unpack8(uint4 u, float* f){
  f[0]=__uint_as_float(u.x<<16); f[1]=__uint_as_float(u.x&0xffff0000u);
  f[2]=__uint_as_float(u.y<<16); f[3]=__uint_as_float(u.y&0xffff0000u);
  f[4]=__uint_as_float(u.z<<16); f[5]=__uint_as_float(u.z&0xffff0000u);
  f[6]=__uint_as_float(u.w<<16); f[7]=__uint_as_float(u.w&0xffff0000u);
}
__device__ __forceinline__ void load48f(const u16* p, float* f){
#pragma unroll
  for (int c=0;c<6;c++){ uint4 u = *(const uint4*)(p + c*8); unpack8(u, f+c*8); }
}
__device__ __forceinline__ float dot48(const float* q, const u16* p){
  float s = 0.f;
#pragma unroll
  for (int c=0;c<6;c++){
    uint4 u = *(const uint4*)(p + c*8); float kf[8]; unpack8(u,kf);
#pragma unroll
    for (int d=0;d<8;d++) s += q[c*8+d]*kf[d];
  }
  return s;
}
__device__ __forceinline__ void pv_acc(float wgt, const u16* vp, float* acc){
#pragma unroll
  for (int c=0;c<6;c++){
    uint4 u = *(const uint4*)(vp + c*8); float vf[8]; unpack8(u,vf);
#pragma unroll
    for (int d=0;d<8;d++) acc[c*8+d] += wgt*vf[d];
  }
}
__device__ __forceinline__ void attn_upd(float s, const u16* vp, float& m, float& l, float* acc){
  float mn = fmaxf(m, s);
  float corr = __expf(m - mn);
  float w = __expf(s - mn);
  l = l*corr + w;
#pragma unroll
  for (int c=0;c<6;c++){
    uint4 u = *(const uint4*)(vp + c*8); float vf[8]; unpack8(u,vf);
#pragma unroll
    for (int d=0;d<8;d++){ acc[c*8+d] = acc[c*8+d]*corr + w*vf[d]; }
  }
  m = mn;
}
__device__ __forceinline__ void store48(u16* p, const float* a, float inv){
#pragma unroll
  for (int c=0;c<6;c++){
    uint4 o;
    o.x = (unsigned)f2b(a[c*8+0]*inv) | ((unsigned)f2b(a[c*8+1]*inv)<<16);
    o.y = (unsigned)f2b(a[c*8+2]*inv) | ((unsigned)f2b(a[c*8+3]*inv)<<16);
    o.z = (unsigned)f2b(a[c*8+4]*inv) | ((unsigned)f2b(a[c*8+5]*inv)<<16);
    o.w = (unsigned)f2b(a[c*8+6]*inv) | ((unsigned)f2b(a[c*8+7]*inv)<<16);
    *(uint4*)(p + c*8) = o;
  }
}

// async global->LDS, 16 bytes per lane
__device__ __forceinline__ void gload16(const u16* g, u16* l){
  __builtin_amdgcn_global_load_lds((const __attribute__((address_space(1))) void*)g,
                                   (__attribute__((address_space(3))) void*)l, 16, 0, 0);
}

// ---------------- wide GEMM (BM=128, 512 thr, 8 waves 4Mx2N): for Npad in {768,1152,1536} ----------------
template<int OUTF32, int RES, int GELU, int NFRAG>
__global__ __launch_bounds__(512, 2) void gemm_mfma(
    const u16* A, int ldA, int aBase, int aRofs, int aSeg, int aStr,
    const u16* __restrict__ Bt, const float* __restrict__ bias,
    void* C, int ldC, int cBase, int cRofs, int cSeg, int cStr,
    int N, int K)
{
  constexpr int GCOLS = NFRAG*32;
  constexpr int BROWS = NFRAG*32;
  constexpr int BSEG  = BROWS/128;
  __shared__ __align__(16) u16 As[2*128*32];
  __shared__ __align__(16) u16 Bs[2*BROWS*32];
  __shared__ int mapA[128];
  __shared__ int mapC[128];
  int tid = threadIdx.x;
  int bm = blockIdx.x, bg = blockIdx.y;
  if (tid < 128){
    int r = bm*128 + tid + aRofs;
    mapA[tid] = aBase + (r/aSeg)*aStr + r%aSeg;
  } else if (tid < 256){
    int t2 = tid - 128;
    int r = bm*128 + t2 + cRofs;
    mapC[t2] = cBase + (r/cSeg)*cStr + r%cSeg;
  }
  __syncthreads();

  int wid = tid>>6, lane = tid&63;
  const u16* aSrc = A + (long)mapA[wid*16 + (lane>>2)]*ldA + ((lane&3)<<3);
  int aDst = (wid*16)*32;
  long nb0 = (long)bg*GCOLS;
  const u16* bSrc[BSEG];
  int bDst[BSEG];
#pragma unroll
  for (int s=0;s<BSEG;s++){
    int br = wid*(BROWS/8) + s*16;
    bSrc[s] = Bt + (nb0 + br + (lane>>2))*(long)K + ((lane&3)<<3);
    bDst[s] = br*32;
  }

  int wr = wid>>1, wc = wid&1;
  int lr = lane&15, kq = lane>>4;
  f32x4 acc[2][NFRAG] = {};

  auto stage = [&](int t, int buf){
    int k0 = t<<5;
    gload16(aSrc + k0, As + buf*(128*32) + aDst);
#pragma unroll
    for (int s=0;s<BSEG;s++)
      gload16(bSrc[s] + k0, Bs + buf*(BROWS*32) + bDst[s]);
  };

  int nst = K>>5;
  stage(0, 0);
  __syncthreads();
  int cur = 0;
  for (int t=0; t<nst; ++t){
    if (t+1 < nst) stage(t+1, cur^1);
    int ao = cur*(128*32), bo = cur*(BROWS*32);
    bf16x8 af0 = *(const bf16x8*)(As + ao + (wr*32 +      lr)*32 + kq*8);
    bf16x8 af1 = *(const bf16x8*)(As + ao + (wr*32 + 16 + lr)*32 + kq*8);
#pragma unroll
    for (int nf=0; nf<NFRAG; ++nf){
      bf16x8 bf = *(const bf16x8*)(Bs + bo + (wc*NFRAG*16 + nf*16 + lr)*32 + kq*8);
      acc[0][nf] = __builtin_amdgcn_mfma_f32_16x16x32_bf16(af0, bf, acc[0][nf], 0,0,0);
      acc[1][nf] = __builtin_amdgcn_mfma_f32_16x16x32_bf16(af1, bf, acc[1][nf], 0,0,0);
    }
    __syncthreads();
    cur ^= 1;
  }

#pragma unroll
  for (int nf=0; nf<NFRAG; ++nf){
    int col = (int)nb0 + wc*NFRAG*16 + nf*16 + lr;
    if (col < N){
      float bv = bias[col];
#pragma unroll
      for (int mf=0; mf<2; ++mf){
#pragma unroll
        for (int jj=0;jj<4;jj++){
          int rt = wr*32 + mf*16 + kq*4 + jj;
          float v = acc[mf][nf][jj] + bv;
          if (GELU){
            float u3 = v*v*v;
            float z2 = 1.5957691216057308f*(v + 0.044715f*u3);
            float e = __expf(-z2);
            v = v / (1.f + e);
          }
          long off = (long)mapC[rt]*ldC + col;
          if (OUTF32){
            float* Cf = (float*)C;
            float r2 = v;
            if (RES) r2 += Cf[off];
            Cf[off] = r2;
          } else {
            ((u16*)C)[off] = f2b(v);
          }
        }
      }
    }
  }
}

// ---------------- narrow GEMM v2 (BM=64, 512 thr, 8 waves 2Mx4N): for Npad in {384,256} ----------------
template<int OUTF32, int RES, int GELU, int LNOUT, int NFRAG>
__global__ __launch_bounds__(512, 4) void gemm_mfma64(
    const u16* A, int ldA, int aBase, int aRofs, int aSeg, int aStr,
    const u16* __restrict__ Bt, const float* __restrict__ bias,
    void* C, int ldC, int cBase, int cRofs, int cSeg, int cStr,
    int N, int K, u16* Hout, float lnEps)
{
  constexpr int GCOLS = NFRAG*64;
  constexpr int BROWS = GCOLS;
  constexpr int BSEG  = BROWS/128;
  __shared__ __align__(16) u16 As[2*64*32];
  __shared__ __align__(16) u16 Bs[2*BROWS*32];
  __shared__ int mapA[64];
  __shared__ int mapC[64];
  int tid = threadIdx.x;
  int bm = blockIdx.x;
  if (tid < 64){
    int r = bm*64 + tid + aRofs;
    mapA[tid] = aBase + (r/aSeg)*aStr + r%aSeg;
  } else if (tid < 128){
    int t2 = tid - 64;
    int r = bm*64 + t2 + cRofs;
    mapC[t2] = cBase + (r/cSeg)*cStr + r%cSeg;
  }
  __syncthreads();

  int wid = tid>>6, lane = tid&63;
  const u16* aSrc = A + (long)mapA[(wid&3)*16 + (lane>>2)]*ldA + ((lane&3)<<3);
  int aDst = ((wid&3)*16)*32;
  const u16* bSrc[BSEG];
  int bDst[BSEG];
#pragma unroll
  for (int s=0;s<BSEG;s++){
    int br = wid*(BROWS/8) + s*16;
    bSrc[s] = Bt + (br + (lane>>2))*(long)K + ((lane&3)<<3);
    bDst[s] = br*32;
  }

  int wr = wid>>2, wc = wid&3;
  int lr = lane&15, kq = lane>>4;
  f32x4 acc[2][NFRAG] = {};

  auto stage = [&](int t, int buf){
    int k0 = t<<5;
    if (wid < 4) gload16(aSrc + k0, As + buf*(64*32) + aDst);
#pragma unroll
    for (int s=0;s<BSEG;s++)
      gload16(bSrc[s] + k0, Bs + buf*(BROWS*32) + bDst[s]);
  };

  int nst = K>>5;
  stage(0, 0);
  __syncthreads();
  int cur = 0;
  for (int t=0; t<nst; ++t){
    if (t+1 < nst) stage(t+1, cur^1);
    int ao = cur*(64*32), bo = cur*(BROWS*32);
    bf16x8 af0 = *(const bf16x8*)(As + ao + (wr*32 +      lr)*32 + kq*8);
    bf16x8 af1 = *(const bf16x8*)(As + ao + (wr*32 + 16 + lr)*32 + kq*8);
#pragma unroll
    for (int nf=0; nf<NFRAG; ++nf){
      bf16x8 bf = *(const bf16x8*)(Bs + bo + (wc*NFRAG*16 + nf*16 + lr)*32 + kq*8);
      acc[0][nf] = __builtin_amdgcn_mfma_f32_16x16x32_bf16(af0, bf, acc[0][nf], 0,0,0);
      acc[1][nf] = __builtin_amdgcn_mfma_f32_16x16x32_bf16(af1, bf, acc[1][nf], 0,0,0);
    }
    __syncthreads();
    cur ^= 1;
  }

  if (LNOUT){
    float sArr[8], qArr[8];
#pragma unroll
    for (int k=0;k<8;k++){ sArr[k]=0.f; qArr[k]=0.f; }
    float* Cf = (float*)C;
#pragma unroll
    for (int nf=0; nf<NFRAG; ++nf){
      int col = wc*NFRAG*16 + nf*16 + lr;
      float bv = bias[col];
#pragma unroll
      for (int mf=0; mf<2; ++mf){
#pragma unroll
        for (int jj=0;jj<4;jj++){
          int rt = wr*32 + mf*16 + kq*4 + jj;
          long off = (long)mapC[rt]*ldC + col;
          float r2 = acc[mf][nf][jj] + bv + Cf[off];
          Cf[off] = r2;
          acc[mf][nf][jj] = r2;
          sArr[mf*4+jj] += r2;
          qArr[mf*4+jj] += r2*r2;
        }
      }
    }
#pragma unroll
    for (int k=0;k<8;k++){
#pragma unroll
      for (int o=1;o<16;o<<=1){ sArr[k] += __shfl_xor(sArr[k],o); qArr[k] += __shfl_xor(qArr[k],o); }
    }
    float* lnp = (float*)As;
    if (lr==0){
#pragma unroll
      for (int mf=0;mf<2;mf++)
#pragma unroll
      for (int jj=0;jj<4;jj++){
        int rt = wr*32 + mf*16 + kq*4 + jj;
        lnp[rt*8 + wc*2 + 0] = sArr[mf*4+jj];
        lnp[rt*8 + wc*2 + 1] = qArr[mf*4+jj];
      }
    }
    __syncthreads();
#pragma unroll
    for (int mf=0;mf<2;mf++){
#pragma unroll
      for (int jj=0;jj<4;jj++){
        int rt = wr*32 + mf*16 + kq*4 + jj;
        float S = lnp[rt*8+0] + lnp[rt*8+2] + lnp[rt*8+4] + lnp[rt*8+6];
        float Q = lnp[rt*8+1] + lnp[rt*8+3] + lnp[rt*8+5] + lnp[rt*8+7];
        float mean = S*(1.f/384.f);
        float var  = Q*(1.f/384.f) - mean*mean;
        float rstd = rsqrtf(var + lnEps);
        long hb = (long)mapC[rt]*HIDD;
#pragma unroll
        for (int nf=0;nf<NFRAG;nf++){
          int col = wc*NFRAG*16 + nf*16 + lr;
          Hout[hb + col] = f2b((acc[mf][nf][jj]-mean)*rstd);
        }
      }
    }
    return;
  }

#pragma unroll
  for (int nf=0; nf<NFRAG; ++nf){
    int col = wc*NFRAG*16 + nf*16 + lr;
    if (col < N){
      float bv = bias[col];
#pragma unroll
      for (int mf=0; mf<2; ++mf){
#pragma unroll
        for (int jj=0;jj<4;jj++){
          int rt = wr*32 + mf*16 + kq*4 + jj;
          float v = acc[mf][nf][jj] + bv;
          if (GELU){
            float u3 = v*v*v;
            float z2 = 1.5957691216057308f*(v + 0.044715f*u3);
            float e = __expf(-z2);
            v = v / (1.f + e);
          }
          long off = (long)mapC[rt]*ldC + col;
          if (OUTF32){
            float* Cf = (float*)C;
            float r2 = v;
            if (RES) r2 += Cf[off];
            Cf[off] = r2;
          } else {
            ((u16*)C)[off] = f2b(v);
          }
        }
      }
    }
  }
}

// ---------------- LayerNorm over 384 (used once, post-assembly) ----------------
__global__ __launch_bounds__(256) void ln_rows(
    const float* __restrict__ X, u16* __restrict__ H, int M)
{
  int wid = threadIdx.x>>6, lane = threadIdx.x&63;
  int r = blockIdx.x*4 + wid;
  if (r >= M) return;
  const float* xp = X + (long)r*HIDD;
  float v[6]; float s=0.f, ss=0.f;
#pragma unroll
  for (int p=0;p<6;p++){ v[p] = xp[lane + 64*p]; s += v[p]; ss += v[p]*v[p]; }
#pragma unroll
  for (int o=32;o>=1;o>>=1){ s += __shfl_xor(s,o); ss += __shfl_xor(ss,o); }
  float mean = s*(1.f/384.f);
  float var  = ss*(1.f/384.f) - mean*mean;
  float rstd = rsqrtf(var + 1e-6f);
  u16* hp = H + (long)r*HIDD;
#pragma unroll
  for (int p=0;p<6;p++){
    int c = lane + 64*p;
    hp[c] = f2b((v[p]-mean)*rstd);
  }
}

// cast f32 rows -> bf16 rows (segmented)
__global__ __launch_bounds__(256) void cast_rows(
    const float* __restrict__ X, u16* __restrict__ H, int M, int base, int seg, int str)
{
  int wid = threadIdx.x>>6, lane = threadIdx.x&63;
  int r = blockIdx.x*4 + wid;
  if (r >= M) return;
  long g = base + (long)(r/seg)*str + r%seg;
  const float* xp = X + g*HIDD;
  u16* hp = H + g*HIDD;
#pragma unroll
  for (int p=0;p<6;p++){ int c = lane + 64*p; hp[c] = f2b(xp[c]); }
}

// elementwise f32 -> bf16
__global__ void cast_arr(const float* __restrict__ S, u16* __restrict__ D, long n){
  long i = (long)blockIdx.x*256 + threadIdx.x;
  if (i < n) D[i] = f2b(S[i]);
}

// broadcast virtual tracks into x
__global__ void set_virt(const float* __restrict__ vtr, float* __restrict__ X){
  int idx = blockIdx.x*256 + threadIdx.x;
  if (idx >= T_STEPS*NVIRT*HIDD) return;
  int c = idx % HIDD;
  int i = (idx / HIDD) % NVIRT;
  int t = idx / (HIDD*NVIRT);
  X[((long)t*NTOT + NREAL + i)*HIDD + c] = vtr[i*HIDD + c];
}

// pack fused QKV biases for all layers
__global__ void pack_bias(const float* __restrict__ qb, const float* __restrict__ kvb,
                          float* __restrict__ fb){
  int j = blockIdx.x;
  for (int idx = threadIdx.x; idx < 3*1152; idx += blockDim.x){
    int s = idx/1152, c = idx%1152;
    float v = (c < 384) ? qb[(size_t)(s*6+j)*384 + c] : kvb[(size_t)(s*6+j)*768 + (c-384)];
    fb[((size_t)j*3 + s)*1152 + c] = v;
  }
}

// combined cross-KV bias for ALL layers in one launch
__global__ __launch_bounds__(768) void kv_bias_all(const float* __restrict__ kvw, const float* __restrict__ kvb,
                                                   const float* __restrict__ ncb, float* __restrict__ cb){
  int c = blockIdx.x, j = blockIdx.y;
  int n = threadIdx.x;
  int cl = c*6 + j;
  const float* W = kvw + (size_t)cl*294912;
  const float* B = ncb + (size_t)cl*384;
  float s = kvb[(size_t)cl*768 + n];
  for (int k=0;k<384;k++) s += B[k]*W[(long)k*768 + n];
  cb[((size_t)j*2 + c)*768 + n] = s;
}

// single transpose-cast (setup only)
__global__ void transpose_cast(const float* __restrict__ src, u16* __restrict__ dst,
                               int K, int N, int Npad)
{
  __shared__ float t[32][33];
  int k0 = blockIdx.x*32, n0 = blockIdx.y*32;
  int tx = threadIdx.x, ty = threadIdx.y;
#pragma unroll
  for (int yy=0; yy<4; yy++){
    int k = k0+ty+8*yy, n = n0+tx;
    t[ty+8*yy][tx] = (k<K && n<N) ? src[(long)k*N+n] : 0.f;
  }
  __syncthreads();
#pragma unroll
  for (int yy=0; yy<4; yy++){
    int n = n0+ty+8*yy, k = k0+tx;
    if (n<Npad && k<K) dst[(long)n*K+k] = f2b(t[tx][ty+8*yy]);
  }
}

// batched transpose-cast with optional per-src-row scale
struct TDesc { const float* src; long sS; u16* dst; long dS; const float* scale; long scS;
               int K, N, Npad, nmat; };
struct TPack { TDesc d[10]; int zo[11]; };

__global__ void transpose_pack(TPack p){
  __shared__ float t[32][33];
  int z = blockIdx.z;
  int di = 0;
  while (di < 9 && z >= p.zo[di+1]) di++;
  TDesc D = p.d[di];
  int mat = z - p.zo[di];
  int k0 = blockIdx.x*32, n0 = blockIdx.y*32;
  if (k0 >= D.K || n0 >= D.Npad) return;
  const float* S = D.src + (long)mat*D.sS;
  u16* Dd = D.dst + (long)mat*D.dS;
  const float* sc = D.scale ? D.scale + (long)mat*D.scS : nullptr;
  int tx = threadIdx.x, ty = threadIdx.y;
#pragma unroll
  for (int yy=0; yy<4; yy++){
    int k = k0+ty+8*yy, n = n0+tx;
    float v = (k<D.K && n<D.N) ? S[(long)k*D.N+n] : 0.f;
    if (sc && k<D.K) v *= sc[k];
    t[ty+8*yy][tx] = v;
  }
  __syncthreads();
#pragma unroll
  for (int yy=0; yy<4; yy++){
    int n = n0+ty+8*yy, k = k0+tx;
    if (n<D.Npad && k<D.K) Dd[(long)n*D.K+k] = f2b(t[tx][ty+8*yy]);
  }
}

// ---------------- attention kernels (two-pass chunked softmax, 256-thr blocks) ----------------
// time self-attn over track group [n0,n0+ngr). 16 keys: single two-pass chunk.
// grid (ngr/16, 8), block 256. thread -> (nl = bx*16 + w*4 + (lane>>4), tq = lane&15)
__global__ __launch_bounds__(256) void attn_time_g(const u16* __restrict__ QKV, u16* __restrict__ O,
                                                   int n0, int ngr){
  int lane = threadIdx.x&63, w = threadIdx.x>>6;
  int nl = blockIdx.x*16 + w*4 + (lane>>4);
  int tq = lane&15;
  int hh = blockIdx.y;
  float qv[48]; load48f(QKV + ((long)tq*ngr + nl)*QKVLD + hh*48, qv);
  float sc[16];
#pragma unroll
  for (int tk=0;tk<16;tk++)
    sc[tk] = dot48(qv, QKV + ((long)tk*ngr + nl)*QKVLD + 384 + hh*48)*ATT_SCALE;
  float m = sc[0];
#pragma unroll
  for (int tk=1;tk<16;tk++) m = fmaxf(m, sc[tk]);
  float l = 0.f;
#pragma unroll
  for (int tk=0;tk<16;tk++){ sc[tk] = __expf(sc[tk]-m); l += sc[tk]; }
  float acc[48];
#pragma unroll
  for (int d=0;d<48;d++) acc[d]=0.f;
#pragma unroll
  for (int tk=0;tk<16;tk++)
    pv_acc(sc[tk], QKV + ((long)tk*ngr + nl)*QKVLD + 768 + hh*48, acc);
  store48(O + ((long)tq*NTOT + n0 + nl)*HIDD + hh*48, acc, 1.f/l);
}

// virt self-attn: 64 keys in 4 chunks of 16. grid (4, 8), block 256 (wave w -> t = bx*4+w)
__global__ __launch_bounds__(256) void attn_virt(const u16* __restrict__ QKV, u16* __restrict__ O){
  int lane = threadIdx.x&63, w = threadIdx.x>>6;
  int t = blockIdx.x*4 + w, hh = blockIdx.y;
  float qv[48]; load48f(QKV + ((long)t*NVIRT + lane)*QKVLD + hh*48, qv);
  float m=-3e38f, l=0.f, acc[48];
#pragma unroll
  for (int d=0;d<48;d++) acc[d]=0.f;
  for (int c0=0;c0<NVIRT;c0+=16){
    float sc[16];
#pragma unroll
    for (int k=0;k<16;k++)
      sc[k] = dot48(qv, QKV + ((long)t*NVIRT + c0+k)*QKVLD + 384 + hh*48)*ATT_SCALE;
    float cm = sc[0];
#pragma unroll
    for (int k=1;k<16;k++) cm = fmaxf(cm, sc[k]);
    float mn = fmaxf(m, cm);
    float corr = __expf(m - mn);
    l *= corr;
#pragma unroll
    for (int d=0;d<48;d++) acc[d] *= corr;
#pragma unroll
    for (int k=0;k<16;k++){
      float wg = __expf(sc[k]-mn); l += wg;
      pv_acc(wg, QKV + ((long)t*NVIRT + c0+k)*QKVLD + 768 + hh*48, acc);
    }
    m = mn;
  }
  store48(O + ((long)t*NTOT + NREAL + lane)*HIDD + hh*48, acc, 1.f/l);
}

// local 6x6 windowed self-attn, time chunk t0 (8 steps). grid (88, 2, 8), block 256 (wave -> tl)
__global__ __launch_bounds__(256) void attn_local_g(const u16* __restrict__ QKV, u16* __restrict__ O, int t0){
  int lane = threadIdx.x&63, w = threadIdx.x>>6;
  if (lane >= 36) return;
  int wh = blockIdx.x/11, ww = blockIdx.x%11;
  int i = lane/6, jc = lane%6;
  int jmax = (ww==10) ? 4 : 6;
  if (jc >= jmax) return;
  int tl = blockIdx.y*4 + w, hh = blockIdx.z;
  int d0 = (wh*6+i)*64 + ww*6+jc;
  float qv[48]; load48f(QKV + ((long)tl*NDENSE + d0)*QKVLD + hh*48, qv);
  float m=-3e38f, l=0.f, acc[48];
#pragma unroll
  for (int dd=0;dd<48;dd++) acc[dd]=0.f;
  for (int i2=0;i2<6;i2++){
    long kbase = (long)tl*NDENSE + (wh*6+i2)*64 + ww*6;
    float sc[6];
#pragma unroll
    for (int j2=0;j2<6;j2++) if (j2<jmax)
      sc[j2] = dot48(qv, QKV + (kbase+j2)*QKVLD + 384 + hh*48)*ATT_SCALE;
    float cm = sc[0];
#pragma unroll
    for (int j2=1;j2<6;j2++) if (j2<jmax) cm = fmaxf(cm, sc[j2]);
    float mn = fmaxf(m, cm);
    float corr = __expf(m - mn);
    l *= corr;
#pragma unroll
    for (int dd=0;dd<48;dd++) acc[dd] *= corr;
#pragma unroll
    for (int j2=0;j2<6;j2++) if (j2<jmax){
      float wg = __expf(sc[j2]-mn); l += wg;
      pv_acc(wg, QKV + (kbase+j2)*QKVLD + 768 + hh*48, acc);
    }
    m = mn;
  }
  store48(O + ((long)(t0+tl)*NTOT + NSPARSE + d0)*HIDD + hh*48, acc, 1.f/l);
}

// cross vr pass1 (unchanged): split 832 keys into 16 segments of 52
__global__ __launch_bounds__(256) void attn_vr_p1(const u16* __restrict__ Q, const u16* __restrict__ KV,
                                                  float* __restrict__ P, int t0){
  int tl = blockIdx.x, hh = blockIdx.y;
  int w = threadIdx.x>>6, lane = threadIdx.x&63;
  int seg = blockIdx.z*4 + w;
  long qr = (long)(t0+tl)*NVIRT + lane;
  float qv[48]; load48f(Q + qr*HIDD + hh*48, qv);
  float m=-3e38f, l=0.f, acc[48];
#pragma unroll
  for (int d=0;d<48;d++) acc[d]=0.f;
  int k0 = seg*52, k1 = k0+52;
  for (int mk=k0; mk<k1; ++mk){
    long kr = (long)tl*NREAL + mk;
    const u16* kp = KV + kr*768 + hh*48;
    float s = dot48(qv, kp)*ATT_SCALE;
    attn_upd(s, kp+384, m, l, acc);
  }
  float* p = P + ((((long)tl*NHEAD + hh)*16 + seg)*64 + lane)*50;
  p[0]=m; p[1]=l;
#pragma unroll
  for (int d=0;d<48;d++) p[2+d]=acc[d];
}

__global__ __launch_bounds__(64) void attn_vr_p2(const float* __restrict__ P, u16* __restrict__ O, int t0){
  int tl = blockIdx.x, hh = blockIdx.y, lane = threadIdx.x;
  const float* pb = P + (((long)tl*NHEAD + hh)*16*64 + lane)*50;
  float M2 = -3e38f;
#pragma unroll
  for (int sg=0;sg<16;sg++) M2 = fmaxf(M2, pb[(long)sg*64*50 + 0]);
  float L=0.f, out[48];
#pragma unroll
  for (int d=0;d<48;d++) out[d]=0.f;
#pragma unroll
  for (int sg=0;sg<16;sg++){
    const float* pp = pb + (long)sg*64*50;
    float c = __expf(pp[0]-M2);
    L += pp[1]*c;
#pragma unroll
    for (int d=0;d<48;d++) out[d] += pp[2+d]*c;
  }
  long orow = (long)(t0+tl)*NTOT + NREAL + lane;
  store48(O + orow*HIDD + hh*48, out, 1.f/L);
}

// cross: real queries over 64 virt keys, 4 chunks of 16. grid (13, 16, 8), block 256.
__global__ __launch_bounds__(256) void attn_cross_rv(const u16* __restrict__ Q, const u16* __restrict__ KV, u16* __restrict__ O){
  int lane = threadIdx.x&63, w = threadIdx.x>>6;
  int t = blockIdx.y, hh = blockIdx.z;
  int n = blockIdx.x*256 + w*64 + lane;
  float qv[48]; load48f(Q + ((long)t*NREAL + n)*HIDD + hh*48, qv);
  float m=-3e38f, l=0.f, acc[48];
#pragma unroll
  for (int d=0;d<48;d++) acc[d]=0.f;
  for (int c0=0;c0<NVIRT;c0+=16){
    float sc[16];
#pragma unroll
    for (int k=0;k<16;k++)
      sc[k] = dot48(qv, KV + ((long)t*NVIRT + c0+k)*768 + hh*48)*ATT_SCALE;
    float cm = sc[0];
#pragma unroll
    for (int k=1;k<16;k++) cm = fmaxf(cm, sc[k]);
    float mn = fmaxf(m, cm);
    float corr = __expf(m - mn);
    l *= corr;
#pragma unroll
    for (int d=0;d<48;d++) acc[d] *= corr;
#pragma unroll
    for (int k=0;k<16;k++){
      float wg = __expf(sc[k]-mn); l += wg;
      pv_acc(wg, KV + ((long)t*NVIRT + c0+k)*768 + 384 + hh*48, acc);
    }
    m = mn;
  }
  store48(O + ((long)t*NTOT + n)*HIDD + hh*48, acc, 1.f/l);
}

// ---------------- host ----------------
static const size_t LW_SAQKV = 0;
static const size_t LW_SAO   = LW_SAQKV + 3ul*442368;
static const size_t LW_SAF1  = LW_SAO   + 3ul*147456;
static const size_t LW_SAF2  = LW_SAF1  + 3ul*589824;
static const size_t LW_CAQ   = LW_SAF2  + 3ul*589824;
static const size_t LW_CAKV  = LW_CAQ   + 2ul*147456;
static const size_t LW_CAO   = LW_CAKV  + 2ul*294912;
static const size_t LW_CAF1  = LW_CAO   + 2ul*147456;
static const size_t LW_CAF2  = LW_CAF1  + 2ul*589824;
static const size_t LW_TOTAL = LW_CAF2  + 2ul*589824;

static const size_t QKV_ELEMS = (size_t)MIDCAP*FFD;      // 41,680,896
static const size_t VRKV_OFF  = 1048576;
static const size_t VRP_OFFB  = 44040192;
static const size_t RVKV_OFF  = 21000000;

extern "C" void kernel_launch(void* const* d_in, const int* in_sizes, int n_in,
                              void* d_out, int out_size, void* d_ws, size_t ws_size,
                              hipStream_t stream)
{
  const float* in_t   = (const float*)d_in[0];
  const float* w_in   = (const float*)d_in[2];
  const float* b_in   = (const float*)d_in[3];
  const float* w_out  = (const float*)d_in[4];
  const float* b_out  = (const float*)d_in[5];
  const float* vtr    = (const float*)d_in[6];
  const float* sa_qw  = (const float*)d_in[7];
  const float* sa_qb  = (const float*)d_in[8];
  const float* sa_kvw = (const float*)d_in[9];
  const float* sa_kvb = (const float*)d_in[10];
  const float* sa_ow  = (const float*)d_in[11];
  const float* sa_ob  = (const float*)d_in[12];
  const float* sa_f1w = (const float*)d_in[13];
  const float* sa_f1b = (const float*)d_in[14];
  const float* sa_f2w = (const float*)d_in[15];
  const float* sa_f2b = (const float*)d_in[16];
  const float* ca_qw  = (const float*)d_in[17];
  const float* ca_qb  = (const float*)d_in[18];
  const float* ca_kvw = (const float*)d_in[19];
  const float* ca_kvb = (const float*)d_in[20];
  const float* ca_ow  = (const float*)d_in[21];
  const float* ca_ob  = (const float*)d_in[22];
  const float* ca_f1w = (const float*)d_in[23];
  const float* ca_f1b = (const float*)d_in[24];
  const float* ca_f2w = (const float*)d_in[25];
  const float* ca_f2b = (const float*)d_in[26];
  const float* ca_ncw = (const float*)d_in[27];
  const float* ca_ncb = (const float*)d_in[28];

  char* ws = (char*)d_ws;
  size_t off = 0;
  auto alloc = [&](size_t bytes)->void*{
    void* p = ws + off;
    off += (bytes + 255) & ~(size_t)255;
    return p;
  };
  float* x   = (float*)alloc((size_t)ROWS_ALL*HIDD*4);
  u16* h     = (u16*)alloc((size_t)ROWS_ALL*HIDD*2);      // always current LN(x)
  u16* qkv   = (u16*)alloc(QKV_ELEMS*2);
  u16* wt    = (u16*)alloc(LW_TOTAL*2);
  float* fb  = (float*)alloc(6ul*3*1152*4);
  float* cb  = (float*)alloc(12ul*768*4);
  u16* mid   = qkv;
  u16* inb   = qkv;
  u16* vrQ   = qkv;
  u16* vrKV  = qkv + VRKV_OFF;
  float* vrP = (float*)((char*)qkv + VRP_OFFB);
  u16* rvQ   = qkv;
  u16* rvKV  = qkv + RVKV_OFF;

  // mode 0=bf16, 1=bf16+gelu, 2=f32, 3=f32+res
  auto gemm = [&](int mode, const u16* A, int ldA, int aBase, int aRofs, int aSeg, int aStr,
                  const u16* Bt, const float* bias,
                  void* C, int ldC, int cBase, int cRofs, int cSeg, int cStr,
                  int M, int Nn, int Npad, int K){
    if (Npad == 384){
      dim3 g(M/64, 1), b(512);
      if (mode==0)      gemm_mfma64<0,0,0,0,6><<<g,b,0,stream>>>(A,ldA,aBase,aRofs,aSeg,aStr,Bt,bias,C,ldC,cBase,cRofs,cSeg,cStr,Nn,K,nullptr,0.f);
      else if (mode==1) gemm_mfma64<0,0,1,0,6><<<g,b,0,stream>>>(A,ldA,aBase,aRofs,aSeg,aStr,Bt,bias,C,ldC,cBase,cRofs,cSeg,cStr,Nn,K,nullptr,0.f);
      else if (mode==2) gemm_mfma64<1,0,0,0,6><<<g,b,0,stream>>>(A,ldA,aBase,aRofs,aSeg,aStr,Bt,bias,C,ldC,cBase,cRofs,cSeg,cStr,Nn,K,nullptr,0.f);
      else              gemm_mfma64<1,1,0,0,6><<<g,b,0,stream>>>(A,ldA,aBase,aRofs,aSeg,aStr,Bt,bias,C,ldC,cBase,cRofs,cSeg,cStr,Nn,K,nullptr,0.f);
    } else if (Npad == 256){
      dim3 g(M/64, 1), b(512);
      gemm_mfma64<1,0,0,0,4><<<g,b,0,stream>>>(A,ldA,aBase,aRofs,aSeg,aStr,Bt,bias,C,ldC,cBase,cRofs,cSeg,cStr,Nn,K,nullptr,0.f);
    } else {
      dim3 g(M/128, Npad/384), b(512);
      if (mode==0)      gemm_mfma<0,0,0,12><<<g,b,0,stream>>>(A,ldA,aBase,aRofs,aSeg,aStr,Bt,bias,C,ldC,cBase,cRofs,cSeg,cStr,Nn,K);
      else if (mode==1) gemm_mfma<0,0,1,12><<<g,b,0,stream>>>(A,ldA,aBase,aRofs,aSeg,aStr,Bt,bias,C,ldC,cBase,cRofs,cSeg,cStr,Nn,K);
      else if (mode==2) gemm_mfma<1,0,0,12><<<g,b,0,stream>>>(A,ldA,aBase,aRofs,aSeg,aStr,Bt,bias,C,ldC,cBase,cRofs,cSeg,cStr,Nn,K);
      else              gemm_mfma<1,1,0,12><<<g,b,0,stream>>>(A,ldA,aBase,aRofs,aSeg,aStr,Bt,bias,C,ldC,cBase,cRofs,cSeg,cStr,Nn,K);
    }
  };
  auto gemmLN = [&](const u16* A, int ldA, int aBase, int aRofs, int aSeg, int aStr,
                    const u16* Bt, const float* bias,
                    float* C, int ldC, int cBase, int cRofs, int cSeg, int cStr,
                    int M, int K){
    dim3 g(M/64, 1), b(512);
    gemm_mfma64<1,1,0,1,6><<<g,b,0,stream>>>(A,ldA,aBase,aRofs,aSeg,aStr,Bt,bias,C,ldC,cBase,cRofs,cSeg,cStr,384,K,h,1e-6f);
  };
  auto mlp = [&](int M, int base, int seg, int str,
                 const u16* f1t, const float* f1bias, const u16* f2t, const float* f2bias){
    for (int r0=0; r0<M; r0+=MIDCAP){
      int Mc = (M-r0 < MIDCAP) ? (M-r0) : MIDCAP;
      gemm(1, h, HIDD, base, r0, seg, str, f1t, f1bias, mid, FFD, 0, 0, IDSEG, 0, Mc, FFD, FFD, HIDD);
      gemmLN(mid, FFD, 0, 0, IDSEG, 0, f2t, f2bias, x, HIDD, base, r0, seg, str, Mc, FFD);
    }
  };

  // ---- input projection + token assembly ----
  {
    transpose_cast<<<dim3(10,12,1), dim3(32,8), 0, stream>>>(w_in, wt, 320, 384, 384);
    pack_bias<<<dim3(6), dim3(512), 0, stream>>>(sa_qb, sa_kvb, fb);
    kv_bias_all<<<dim3(2,6), dim3(768), 0, stream>>>(ca_kvw, ca_kvb, ca_ncb, cb);
    long nin = (long)T_STEPS*NREAL*320;
    cast_arr<<<dim3((unsigned)((nin+255)/256)), dim3(256), 0, stream>>>(in_t, inb, nin);
    set_virt<<<dim3((T_STEPS*NVIRT*HIDD+255)/256), dim3(256), 0, stream>>>(vtr, x);
    gemm(2, inb, 320, 0,0,IDSEG,0, wt, b_in, x, HIDD, 0,0,NREAL,NTOT, T_STEPS*NREAL, 384, 384, 320);
    ln_rows<<<dim3((ROWS_ALL+3)/4), dim3(256), 0, stream>>>(x, h, ROWS_ALL);
  }

  // ---- 6 layers ----
  for (int j=0; j<6; ++j){
    TPack tp;
    auto setd = [&](int i, const float* src, long sS, u16* dst, long dS,
                    const float* scale, long scS, int K, int N, int Npad, int nmat){
      tp.d[i] = TDesc{src, sS, dst, dS, scale, scS, K, N, Npad, nmat};
    };
    setd(0, sa_qw  + (size_t)j*147456, 6l*147456, wt+LW_SAQKV,        442368, nullptr, 0, 384, 384,  384,  3);
    setd(1, sa_kvw + (size_t)j*294912, 6l*294912, wt+LW_SAQKV+147456, 442368, nullptr, 0, 384, 768,  768,  3);
    setd(2, sa_ow  + (size_t)j*147456, 6l*147456, wt+LW_SAO,  147456, nullptr, 0, 384, 384,  384,  3);
    setd(3, sa_f1w + (size_t)j*589824, 6l*589824, wt+LW_SAF1, 589824, nullptr, 0, 384, 1536, 1536, 3);
    setd(4, sa_f2w + (size_t)j*589824, 6l*589824, wt+LW_SAF2, 589824, nullptr, 0, 1536,384,  384,  3);
    setd(5, ca_qw  + (size_t)j*147456, 6l*147456, wt+LW_CAQ,  147456, nullptr, 0, 384, 384,  384,  2);
    setd(6, ca_kvw + (size_t)j*294912, 6l*294912, wt+LW_CAKV, 294912, ca_ncw + (size_t)j*384, 6l*384, 384, 768, 768, 2);
    setd(7, ca_ow  + (size_t)j*147456, 6l*147456, wt+LW_CAO,  147456, nullptr, 0, 384, 384,  384,  2);
    setd(8, ca_f1w + (size_t)j*589824, 6l*589824, wt+LW_CAF1, 589824, nullptr, 0, 384, 1536, 1536, 2);
    setd(9, ca_f2w + (size_t)j*589824, 6l*589824, wt+LW_CAF2, 589824, nullptr, 0, 1536,384,  384,  2);
    int zs = 0;
    for (int i=0;i<10;i++){ tp.zo[i] = zs; zs += tp.d[i].nmat; }
    tp.zo[10] = zs;
    transpose_pack<<<dim3(48,48,25), dim3(32,8), 0, stream>>>(tp);
    const float* fbL = fb + (size_t)j*3*1152;
    const float* cbL = cb + (size_t)j*2*768;

    // ===== self over time: h = LN(x) for all rows =====
    {
      int sl = 0*6 + j;
      for (int g2=0; g2<2; ++g2){
        int n0 = g2*NG;
        gemm(0, h, HIDD, n0,0,NG,NTOT, wt+LW_SAQKV, fbL, qkv, QKVLD, 0,0,IDSEG,0, T_STEPS*NG, QKVLD, QKVLD, 384);
        attn_time_g<<<dim3(NG/16, NHEAD), 256, 0, stream>>>(qkv, h, n0, NG);
      }
      gemmLN(h, HIDD, 0,0,IDSEG,0, wt+LW_SAO, sa_ob+sl*384, x, HIDD, 0,0,IDSEG,0, ROWS_ALL, 384);
      mlp(ROWS_ALL, 0, IDSEG, 0, wt+LW_SAF1, sa_f1b+sl*1536, wt+LW_SAF2, sa_f2b+sl*384);
    }

    // ===== cross: virt queries <- real context (ctx LN folded into KV weights) =====
    {
      int cl = 0*6 + j;
      gemm(0, h, HIDD, NREAL,0,NVIRT,NTOT, wt+LW_CAQ, ca_qb+cl*384, vrQ, HIDD, 0,0,IDSEG,0, T_STEPS*NVIRT, 384,384,384);
      for (int tc=0; tc<T_STEPS; tc+=8){
        gemm(0, h, HIDD, tc*NTOT,0,NREAL,NTOT, wt+LW_CAKV, cbL, vrKV, 768, 0,0,IDSEG,0, 8*NREAL, 768,768,384);
        attn_vr_p1<<<dim3(8, NHEAD, 4), 256, 0, stream>>>(vrQ, vrKV, vrP, tc);
        attn_vr_p2<<<dim3(8, NHEAD),     64, 0, stream>>>(vrP, h, tc);
      }
      gemmLN(h, HIDD, NREAL,0,NVIRT,NTOT, wt+LW_CAO, ca_ob+cl*384, x, HIDD, NREAL,0,NVIRT,NTOT, T_STEPS*NVIRT, 384);
      mlp(T_STEPS*NVIRT, NREAL, NVIRT, NTOT, wt+LW_CAF1, ca_f1b+cl*1536, wt+LW_CAF2, ca_f2b+cl*384);
    }

    // ===== self over virt tokens =====
    {
      int sl = 1*6 + j;
      gemm(0, h, HIDD, NREAL,0,NVIRT,NTOT, wt+LW_SAQKV+1ul*442368, fbL+1152, qkv, QKVLD, 0,0,IDSEG,0, T_STEPS*NVIRT, QKVLD, QKVLD, 384);
      attn_virt<<<dim3(4, NHEAD), 256, 0, stream>>>(qkv, h);
      gemmLN(h, HIDD, NREAL,0,NVIRT,NTOT, wt+LW_SAO+1ul*147456, sa_ob+sl*384, x, HIDD, NREAL,0,NVIRT,NTOT, T_STEPS*NVIRT, 384);
      mlp(T_STEPS*NVIRT, NREAL, NVIRT, NTOT, wt+LW_SAF1+1ul*589824, sa_f1b+sl*1536, wt+LW_SAF2+1ul*589824, sa_f2b+sl*384);
    }

    // ===== local windowed self over dense tokens =====
    {
      int sl = 2*6 + j;
      for (int tc=0; tc<T_STEPS; tc+=8){
        gemm(0, h, HIDD, tc*NTOT+NSPARSE,0,NDENSE,NTOT, wt+LW_SAQKV+2ul*442368, fbL+2304, qkv, QKVLD, 0,0,IDSEG,0, 8*NDENSE, QKVLD, QKVLD, 384);
        attn_local_g<<<dim3(88, 2, NHEAD), 256, 0, stream>>>(qkv, h, tc);
      }
      gemmLN(h, HIDD, NSPARSE,0,NDENSE,NTOT, wt+LW_SAO+2ul*147456, sa_ob+sl*384, x, HIDD, NSPARSE,0,NDENSE,NTOT, T_STEPS*NDENSE, 384);
      mlp(T_STEPS*NDENSE, NSPARSE, NDENSE, NTOT, wt+LW_SAF1+2ul*589824, sa_f1b+sl*1536, wt+LW_SAF2+2ul*589824, sa_f2b+sl*384);
    }

    // ===== cross: real queries <- virt context (ctx LN folded into KV weights) =====
    {
      int cl = 1*6 + j;
      gemm(0, h, HIDD, NREAL,0,NVIRT,NTOT, wt+LW_CAKV+1ul*294912, cbL+768, rvKV, 768, 0,0,IDSEG,0, T_STEPS*NVIRT, 768,768,384);
      gemm(0, h, HIDD, 0,0,NREAL,NTOT, wt+LW_CAQ+1ul*147456, ca_qb+cl*384, rvQ, HIDD, 0,0,IDSEG,0, T_STEPS*NREAL, 384,384,384);
      attn_cross_rv<<<dim3(NREAL/256, T_STEPS, NHEAD), 256, 0, stream>>>(rvQ, rvKV, h);
      gemmLN(h, HIDD, 0,0,NREAL,NTOT, wt+LW_CAO+1ul*147456, ca_ob+cl*384, x, HIDD, 0,0,NREAL,NTOT, T_STEPS*NREAL, 384);
      mlp(T_STEPS*NREAL, 0, NREAL, NTOT, wt+LW_CAF1+1ul*589824, ca_f1b+cl*1536, wt+LW_CAF2+1ul*589824, ca_f2b+cl*384);
    }
  }

  // ---- output projection ----
  transpose_cast<<<dim3(12,8,1), dim3(32,8), 0, stream>>>(w_out, wt, 384, 130, 256);
  cast_rows<<<dim3((T_STEPS*NREAL+3)/4), dim3(256), 0, stream>>>(x, h, T_STEPS*NREAL, 0, NREAL, NTOT);
  gemm(2, h, HIDD, 0,0,NREAL,NTOT, wt, b_out, d_out, 130, 0,0,IDSEG,0, T_STEPS*NREAL, 130, 256, 384);
}

// Round 13
// 13384.288 us; speedup vs baseline: 1.1243x; 1.1243x over previous
//
#include <hip/hip_runtime.h>

typedef unsigned short u16;

#define T_STEPS 16
#define NREAL   3328
#define NVIRT   64
#define NTOT    3392
#define HIDD    384
#define FFD     1536
#define NSPARSE 256
#define NDENSE  3072
#define ROWS_ALL (T_STEPS*NTOT)   /* 54272 */
#define NHEAD   8
#define ATT_SCALE 0.14433756729740643f
#define IDSEG   (1<<30)
#define MIDCAP  27136
#define NG      1696
#define QKVLD   1152

using bf16x8 = __attribute__((ext_vector_type(8))) short;
using f32x4  = __attribute__((ext_vector_type(4))) float;

// ---------------- device helpers ----------------
__device__ __forceinline__ u16 f2b(float f){
  unsigned u = __float_as_uint(f);
  return (u16)((u + 0x7fffu + ((u>>16)&1u)) >> 16);
}
__device__ __forceinline__ void unpack8(uint4 u, float* f){
  f[0]=__uint_as_float(u.x<<16); f[1]=__uint_as_float(u.x&0xffff0000u);
  f[2]=__uint_as_float(u.y<<16); f[3]=__uint_as_float(u.y&0xffff0000u);
  f[4]=__uint_as_float(u.z<<16); f[5]=__uint_as_float(u.z&0xffff0000u);
  f[6]=__uint_as_float(u.w<<16); f[7]=__uint_as_float(u.w&0xffff0000u);
}
__device__ __forceinline__ void load48f(const u16* p, float* f){
#pragma unroll
  for (int c=0;c<6;c++){ uint4 u = *(const uint4*)(p + c*8); unpack8(u, f+c*8); }
}
__device__ __forceinline__ float dot48(const float* q, const u16* p){
  float s = 0.f;
#pragma unroll
  for (int c=0;c<6;c++){
    uint4 u = *(const uint4*)(p + c*8); float kf[8]; unpack8(u,kf);
#pragma unroll
    for (int d=0;d<8;d++) s += q[c*8+d]*kf[d];
  }
  return s;
}
__device__ __forceinline__ void attn_upd(float s, const u16* vp, float& m, float& l, float* acc){
  float mn = fmaxf(m, s);
  float corr = __expf(m - mn);
  float w = __expf(s - mn);
  l = l*corr + w;
#pragma unroll
  for (int c=0;c<6;c++){
    uint4 u = *(const uint4*)(vp + c*8); float vf[8]; unpack8(u,vf);
#pragma unroll
    for (int d=0;d<8;d++){ acc[c*8+d] = acc[c*8+d]*corr + w*vf[d]; }
  }
  m = mn;
}
__device__ __forceinline__ void store48(u16* p, const float* a, float inv){
#pragma unroll
  for (int c=0;c<6;c++){
    uint4 o;
    o.x = (unsigned)f2b(a[c*8+0]*inv) | ((unsigned)f2b(a[c*8+1]*inv)<<16);
    o.y = (unsigned)f2b(a[c*8+2]*inv) | ((unsigned)f2b(a[c*8+3]*inv)<<16);
    o.z = (unsigned)f2b(a[c*8+4]*inv) | ((unsigned)f2b(a[c*8+5]*inv)<<16);
    o.w = (unsigned)f2b(a[c*8+6]*inv) | ((unsigned)f2b(a[c*8+7]*inv)<<16);
    *(uint4*)(p + c*8) = o;
  }
}

// async global->LDS, 16 bytes per lane
__device__ __forceinline__ void gload16(const u16* g, u16* l){
  __builtin_amdgcn_global_load_lds((const __attribute__((address_space(1))) void*)g,
                                   (__attribute__((address_space(3))) void*)l, 16, 0, 0);
}

// ---------------- wide GEMM (BM=128, 512 thr, 8 waves 4Mx2N): for Npad in {768,1152,1536} ----------------
template<int OUTF32, int RES, int GELU, int NFRAG>
__global__ __launch_bounds__(512, 2) void gemm_mfma(
    const u16* A, int ldA, int aBase, int aRofs, int aSeg, int aStr,
    const u16* __restrict__ Bt, const float* __restrict__ bias,
    void* C, int ldC, int cBase, int cRofs, int cSeg, int cStr,
    int N, int K)
{
  constexpr int GCOLS = NFRAG*32;
  constexpr int BROWS = NFRAG*32;
  constexpr int BSEG  = BROWS/128;
  __shared__ __align__(16) u16 As[2*128*32];
  __shared__ __align__(16) u16 Bs[2*BROWS*32];
  __shared__ int mapA[128];
  __shared__ int mapC[128];
  int tid = threadIdx.x;
  int bm = blockIdx.x, bg = blockIdx.y;
  if (tid < 128){
    int r = bm*128 + tid + aRofs;
    mapA[tid] = aBase + (r/aSeg)*aStr + r%aSeg;
  } else if (tid < 256){
    int t2 = tid - 128;
    int r = bm*128 + t2 + cRofs;
    mapC[t2] = cBase + (r/cSeg)*cStr + r%cSeg;
  }
  __syncthreads();

  int wid = tid>>6, lane = tid&63;
  const u16* aSrc = A + (long)mapA[wid*16 + (lane>>2)]*ldA + ((lane&3)<<3);
  int aDst = (wid*16)*32;
  long nb0 = (long)bg*GCOLS;
  const u16* bSrc[BSEG];
  int bDst[BSEG];
#pragma unroll
  for (int s=0;s<BSEG;s++){
    int br = wid*(BROWS/8) + s*16;
    bSrc[s] = Bt + (nb0 + br + (lane>>2))*(long)K + ((lane&3)<<3);
    bDst[s] = br*32;
  }

  int wr = wid>>1, wc = wid&1;
  int lr = lane&15, kq = lane>>4;
  f32x4 acc[2][NFRAG] = {};

  auto stage = [&](int t, int buf){
    int k0 = t<<5;
    gload16(aSrc + k0, As + buf*(128*32) + aDst);
#pragma unroll
    for (int s=0;s<BSEG;s++)
      gload16(bSrc[s] + k0, Bs + buf*(BROWS*32) + bDst[s]);
  };

  int nst = K>>5;
  stage(0, 0);
  __syncthreads();
  int cur = 0;
  for (int t=0; t<nst; ++t){
    if (t+1 < nst) stage(t+1, cur^1);
    int ao = cur*(128*32), bo = cur*(BROWS*32);
    bf16x8 af0 = *(const bf16x8*)(As + ao + (wr*32 +      lr)*32 + kq*8);
    bf16x8 af1 = *(const bf16x8*)(As + ao + (wr*32 + 16 + lr)*32 + kq*8);
#pragma unroll
    for (int nf=0; nf<NFRAG; ++nf){
      bf16x8 bf = *(const bf16x8*)(Bs + bo + (wc*NFRAG*16 + nf*16 + lr)*32 + kq*8);
      acc[0][nf] = __builtin_amdgcn_mfma_f32_16x16x32_bf16(af0, bf, acc[0][nf], 0,0,0);
      acc[1][nf] = __builtin_amdgcn_mfma_f32_16x16x32_bf16(af1, bf, acc[1][nf], 0,0,0);
    }
    __syncthreads();
    cur ^= 1;
  }

#pragma unroll
  for (int nf=0; nf<NFRAG; ++nf){
    int col = (int)nb0 + wc*NFRAG*16 + nf*16 + lr;
    if (col < N){
      float bv = bias[col];
#pragma unroll
      for (int mf=0; mf<2; ++mf){
#pragma unroll
        for (int jj=0;jj<4;jj++){
          int rt = wr*32 + mf*16 + kq*4 + jj;
          float v = acc[mf][nf][jj] + bv;
          if (GELU){
            float u3 = v*v*v;
            float z2 = 1.5957691216057308f*(v + 0.044715f*u3);
            float e = __expf(-z2);
            v = v / (1.f + e);
          }
          long off = (long)mapC[rt]*ldC + col;
          if (OUTF32){
            float* Cf = (float*)C;
            float r2 = v;
            if (RES) r2 += Cf[off];
            Cf[off] = r2;
          } else {
            ((u16*)C)[off] = f2b(v);
          }
        }
      }
    }
  }
}

// ---------------- narrow GEMM v2 (BM=64, 512 thr, 8 waves 2Mx4N): for Npad in {384,256} ----------------
// LNOUT (GCOLS==N==384, RES==1): epilogue computes per-row LN of final residual rows -> Hout bf16.
template<int OUTF32, int RES, int GELU, int LNOUT, int NFRAG>
__global__ __launch_bounds__(512, 4) void gemm_mfma64(
    const u16* A, int ldA, int aBase, int aRofs, int aSeg, int aStr,
    const u16* __restrict__ Bt, const float* __restrict__ bias,
    void* C, int ldC, int cBase, int cRofs, int cSeg, int cStr,
    int N, int K, u16* Hout, float lnEps)
{
  constexpr int GCOLS = NFRAG*64;
  constexpr int BROWS = GCOLS;
  constexpr int BSEG  = BROWS/128;
  __shared__ __align__(16) u16 As[2*64*32];
  __shared__ __align__(16) u16 Bs[2*BROWS*32];
  __shared__ int mapA[64];
  __shared__ int mapC[64];
  int tid = threadIdx.x;
  int bm = blockIdx.x;
  if (tid < 64){
    int r = bm*64 + tid + aRofs;
    mapA[tid] = aBase + (r/aSeg)*aStr + r%aSeg;
  } else if (tid < 128){
    int t2 = tid - 64;
    int r = bm*64 + t2 + cRofs;
    mapC[t2] = cBase + (r/cSeg)*cStr + r%cSeg;
  }
  __syncthreads();

  int wid = tid>>6, lane = tid&63;
  const u16* aSrc = A + (long)mapA[(wid&3)*16 + (lane>>2)]*ldA + ((lane&3)<<3);
  int aDst = ((wid&3)*16)*32;
  const u16* bSrc[BSEG];
  int bDst[BSEG];
#pragma unroll
  for (int s=0;s<BSEG;s++){
    int br = wid*(BROWS/8) + s*16;
    bSrc[s] = Bt + (br + (lane>>2))*(long)K + ((lane&3)<<3);
    bDst[s] = br*32;
  }

  int wr = wid>>2, wc = wid&3;
  int lr = lane&15, kq = lane>>4;
  f32x4 acc[2][NFRAG] = {};

  auto stage = [&](int t, int buf){
    int k0 = t<<5;
    if (wid < 4) gload16(aSrc + k0, As + buf*(64*32) + aDst);
#pragma unroll
    for (int s=0;s<BSEG;s++)
      gload16(bSrc[s] + k0, Bs + buf*(BROWS*32) + bDst[s]);
  };

  int nst = K>>5;
  stage(0, 0);
  __syncthreads();
  int cur = 0;
  for (int t=0; t<nst; ++t){
    if (t+1 < nst) stage(t+1, cur^1);
    int ao = cur*(64*32), bo = cur*(BROWS*32);
    bf16x8 af0 = *(const bf16x8*)(As + ao + (wr*32 +      lr)*32 + kq*8);
    bf16x8 af1 = *(const bf16x8*)(As + ao + (wr*32 + 16 + lr)*32 + kq*8);
#pragma unroll
    for (int nf=0; nf<NFRAG; ++nf){
      bf16x8 bf = *(const bf16x8*)(Bs + bo + (wc*NFRAG*16 + nf*16 + lr)*32 + kq*8);
      acc[0][nf] = __builtin_amdgcn_mfma_f32_16x16x32_bf16(af0, bf, acc[0][nf], 0,0,0);
      acc[1][nf] = __builtin_amdgcn_mfma_f32_16x16x32_bf16(af1, bf, acc[1][nf], 0,0,0);
    }
    __syncthreads();
    cur ^= 1;
  }

  if (LNOUT){
    float sArr[8], qArr[8];
#pragma unroll
    for (int k=0;k<8;k++){ sArr[k]=0.f; qArr[k]=0.f; }
    float* Cf = (float*)C;
#pragma unroll
    for (int nf=0; nf<NFRAG; ++nf){
      int col = wc*NFRAG*16 + nf*16 + lr;
      float bv = bias[col];
#pragma unroll
      for (int mf=0; mf<2; ++mf){
#pragma unroll
        for (int jj=0;jj<4;jj++){
          int rt = wr*32 + mf*16 + kq*4 + jj;
          long off = (long)mapC[rt]*ldC + col;
          float r2 = acc[mf][nf][jj] + bv + Cf[off];
          Cf[off] = r2;
          acc[mf][nf][jj] = r2;
          sArr[mf*4+jj] += r2;
          qArr[mf*4+jj] += r2*r2;
        }
      }
    }
#pragma unroll
    for (int k=0;k<8;k++){
#pragma unroll
      for (int o=1;o<16;o<<=1){ sArr[k] += __shfl_xor(sArr[k],o); qArr[k] += __shfl_xor(qArr[k],o); }
    }
    float* lnp = (float*)As;
    if (lr==0){
#pragma unroll
      for (int mf=0;mf<2;mf++)
#pragma unroll
      for (int jj=0;jj<4;jj++){
        int rt = wr*32 + mf*16 + kq*4 + jj;
        lnp[rt*8 + wc*2 + 0] = sArr[mf*4+jj];
        lnp[rt*8 + wc*2 + 1] = qArr[mf*4+jj];
      }
    }
    __syncthreads();
#pragma unroll
    for (int mf=0;mf<2;mf++){
#pragma unroll
      for (int jj=0;jj<4;jj++){
        int rt = wr*32 + mf*16 + kq*4 + jj;
        float S = lnp[rt*8+0] + lnp[rt*8+2] + lnp[rt*8+4] + lnp[rt*8+6];
        float Q = lnp[rt*8+1] + lnp[rt*8+3] + lnp[rt*8+5] + lnp[rt*8+7];
        float mean = S*(1.f/384.f);
        float var  = Q*(1.f/384.f) - mean*mean;
        float rstd = rsqrtf(var + lnEps);
        long hb = (long)mapC[rt]*HIDD;
#pragma unroll
        for (int nf=0;nf<NFRAG;nf++){
          int col = wc*NFRAG*16 + nf*16 + lr;
          Hout[hb + col] = f2b((acc[mf][nf][jj]-mean)*rstd);
        }
      }
    }
    return;
  }

#pragma unroll
  for (int nf=0; nf<NFRAG; ++nf){
    int col = wc*NFRAG*16 + nf*16 + lr;
    if (col < N){
      float bv = bias[col];
#pragma unroll
      for (int mf=0; mf<2; ++mf){
#pragma unroll
        for (int jj=0;jj<4;jj++){
          int rt = wr*32 + mf*16 + kq*4 + jj;
          float v = acc[mf][nf][jj] + bv;
          if (GELU){
            float u3 = v*v*v;
            float z2 = 1.5957691216057308f*(v + 0.044715f*u3);
            float e = __expf(-z2);
            v = v / (1.f + e);
          }
          long off = (long)mapC[rt]*ldC + col;
          if (OUTF32){
            float* Cf = (float*)C;
            float r2 = v;
            if (RES) r2 += Cf[off];
            Cf[off] = r2;
          } else {
            ((u16*)C)[off] = f2b(v);
          }
        }
      }
    }
  }
}

// ---------------- LayerNorm over 384 (used once, post-assembly) ----------------
__global__ __launch_bounds__(256) void ln_rows(
    const float* __restrict__ X, u16* __restrict__ H, int M)
{
  int wid = threadIdx.x>>6, lane = threadIdx.x&63;
  int r = blockIdx.x*4 + wid;
  if (r >= M) return;
  const float* xp = X + (long)r*HIDD;
  float v[6]; float s=0.f, ss=0.f;
#pragma unroll
  for (int p=0;p<6;p++){ v[p] = xp[lane + 64*p]; s += v[p]; ss += v[p]*v[p]; }
#pragma unroll
  for (int o=32;o>=1;o>>=1){ s += __shfl_xor(s,o); ss += __shfl_xor(ss,o); }
  float mean = s*(1.f/384.f);
  float var  = ss*(1.f/384.f) - mean*mean;
  float rstd = rsqrtf(var + 1e-6f);
  u16* hp = H + (long)r*HIDD;
#pragma unroll
  for (int p=0;p<6;p++){
    int c = lane + 64*p;
    hp[c] = f2b((v[p]-mean)*rstd);
  }
}

// cast f32 rows -> bf16 rows (segmented)
__global__ __launch_bounds__(256) void cast_rows(
    const float* __restrict__ X, u16* __restrict__ H, int M, int base, int seg, int str)
{
  int wid = threadIdx.x>>6, lane = threadIdx.x&63;
  int r = blockIdx.x*4 + wid;
  if (r >= M) return;
  long g = base + (long)(r/seg)*str + r%seg;
  const float* xp = X + g*HIDD;
  u16* hp = H + g*HIDD;
#pragma unroll
  for (int p=0;p<6;p++){ int c = lane + 64*p; hp[c] = f2b(xp[c]); }
}

// elementwise f32 -> bf16
__global__ void cast_arr(const float* __restrict__ S, u16* __restrict__ D, long n){
  long i = (long)blockIdx.x*256 + threadIdx.x;
  if (i < n) D[i] = f2b(S[i]);
}

// broadcast virtual tracks into x
__global__ void set_virt(const float* __restrict__ vtr, float* __restrict__ X){
  int idx = blockIdx.x*256 + threadIdx.x;
  if (idx >= T_STEPS*NVIRT*HIDD) return;
  int c = idx % HIDD;
  int i = (idx / HIDD) % NVIRT;
  int t = idx / (HIDD*NVIRT);
  X[((long)t*NTOT + NREAL + i)*HIDD + c] = vtr[i*HIDD + c];
}

// pack fused QKV biases for all layers: fb[j][s][1152] = [qb(384); kvb(768)]
__global__ void pack_bias(const float* __restrict__ qb, const float* __restrict__ kvb,
                          float* __restrict__ fb){
  int j = blockIdx.x;
  for (int idx = threadIdx.x; idx < 3*1152; idx += blockDim.x){
    int s = idx/1152, c = idx%1152;
    float v = (c < 384) ? qb[(size_t)(s*6+j)*384 + c] : kvb[(size_t)(s*6+j)*768 + (c-384)];
    fb[((size_t)j*3 + s)*1152 + c] = v;
  }
}

// combined cross-KV bias for ALL layers in one launch:
// cb[j][set][n] = ca_kvb[set*6+j][n] + sum_k ncb[set*6+j][k]*kvw[set*6+j][k][n]
__global__ __launch_bounds__(768) void kv_bias_all(const float* __restrict__ kvw, const float* __restrict__ kvb,
                                                   const float* __restrict__ ncb, float* __restrict__ cb){
  int c = blockIdx.x, j = blockIdx.y;
  int n = threadIdx.x;
  int cl = c*6 + j;
  const float* W = kvw + (size_t)cl*294912;
  const float* B = ncb + (size_t)cl*384;
  float s = kvb[(size_t)cl*768 + n];
  for (int k=0;k<384;k++) s += B[k]*W[(long)k*768 + n];
  cb[((size_t)j*2 + c)*768 + n] = s;
}

// single transpose-cast (setup only): src [K][N] f32 -> dst [Npad][K] bf16
__global__ void transpose_cast(const float* __restrict__ src, u16* __restrict__ dst,
                               int K, int N, int Npad)
{
  __shared__ float t[32][33];
  int k0 = blockIdx.x*32, n0 = blockIdx.y*32;
  int tx = threadIdx.x, ty = threadIdx.y;
#pragma unroll
  for (int yy=0; yy<4; yy++){
    int k = k0+ty+8*yy, n = n0+tx;
    t[ty+8*yy][tx] = (k<K && n<N) ? src[(long)k*N+n] : 0.f;
  }
  __syncthreads();
#pragma unroll
  for (int yy=0; yy<4; yy++){
    int n = n0+ty+8*yy, k = k0+tx;
    if (n<Npad && k<K) dst[(long)n*K+k] = f2b(t[tx][ty+8*yy]);
  }
}

// batched transpose-cast with optional per-src-row scale: 10 descriptors, one launch.
struct TDesc { const float* src; long sS; u16* dst; long dS; const float* scale; long scS;
               int K, N, Npad, nmat; };
struct TPack { TDesc d[10]; int zo[11]; };

__global__ void transpose_pack(TPack p){
  __shared__ float t[32][33];
  int z = blockIdx.z;
  int di = 0;
  while (di < 9 && z >= p.zo[di+1]) di++;
  TDesc D = p.d[di];
  int mat = z - p.zo[di];
  int k0 = blockIdx.x*32, n0 = blockIdx.y*32;
  if (k0 >= D.K || n0 >= D.Npad) return;
  const float* S = D.src + (long)mat*D.sS;
  u16* Dd = D.dst + (long)mat*D.dS;
  const float* sc = D.scale ? D.scale + (long)mat*D.scS : nullptr;
  int tx = threadIdx.x, ty = threadIdx.y;
#pragma unroll
  for (int yy=0; yy<4; yy++){
    int k = k0+ty+8*yy, n = n0+tx;
    float v = (k<D.K && n<D.N) ? S[(long)k*D.N+n] : 0.f;
    if (sc && k<D.K) v *= sc[k];
    t[ty+8*yy][tx] = v;
  }
  __syncthreads();
#pragma unroll
  for (int yy=0; yy<4; yy++){
    int n = n0+ty+8*yy, k = k0+tx;
    if (n<D.Npad && k<D.K) Dd[(long)n*D.K+k] = f2b(t[tx][ty+8*yy]);
  }
}

// ---------------- attention kernels (r10-proven 64-thread streaming forms) ----------------
// time self-attn over track group [n0,n0+NG). QKV compact [t*NG+nl][1152]; O global.
__global__ __launch_bounds__(64) void attn_time_g(const u16* __restrict__ QKV, u16* __restrict__ O, int n0){
  int lane = threadIdx.x;
  int nl = blockIdx.x*4 + (lane>>4);
  int tq = lane&15;
  int hh = blockIdx.y;
  long qc = (long)tq*NG + nl;
  float qv[48]; load48f(QKV + qc*QKVLD + hh*48, qv);
  float m=-3e38f, l=0.f, acc[48];
#pragma unroll
  for (int d=0;d<48;d++) acc[d]=0.f;
  for (int tk=0;tk<T_STEPS;tk++){
    long kr = (long)tk*NG + nl;
    const u16* kp = QKV + kr*QKVLD + 384 + hh*48;
    float s = dot48(qv, kp)*ATT_SCALE;
    attn_upd(s, kp+384, m, l, acc);
  }
  long qg = (long)tq*NTOT + n0 + nl;
  store48(O + qg*HIDD + hh*48, acc, 1.f/l);
}

__global__ __launch_bounds__(64) void attn_virt(const u16* __restrict__ QKV, u16* __restrict__ O){
  int lane = threadIdx.x;
  int t = blockIdx.x, hh = blockIdx.y;
  long qr = (long)t*NVIRT + lane;
  float qv[48]; load48f(QKV + qr*QKVLD + hh*48, qv);
  float m=-3e38f, l=0.f, acc[48];
#pragma unroll
  for (int d=0;d<48;d++) acc[d]=0.f;
  for (int tk=0;tk<NVIRT;tk++){
    long kr = (long)t*NVIRT + tk;
    const u16* kp = QKV + kr*QKVLD + 384 + hh*48;
    float s = dot48(qv, kp)*ATT_SCALE;
    attn_upd(s, kp+384, m, l, acc);
  }
  long orow = (long)t*NTOT + NREAL + lane;
  store48(O + orow*HIDD + hh*48, acc, 1.f/l);
}

__global__ __launch_bounds__(64) void attn_local_g(const u16* __restrict__ QKV, u16* __restrict__ O, int t0){
  int lane = threadIdx.x;
  if (lane >= 36) return;
  int wh = blockIdx.x/11, ww = blockIdx.x%11;
  int i = lane/6, jc = lane%6;
  int jmax = (ww==10) ? 4 : 6;
  if (jc >= jmax) return;
  int tl = blockIdx.y, hh = blockIdx.z;
  int d0 = (wh*6+i)*64 + ww*6+jc;
  long qr = (long)tl*NDENSE + d0;
  float qv[48]; load48f(QKV + qr*QKVLD + hh*48, qv);
  float m=-3e38f, l=0.f, acc[48];
#pragma unroll
  for (int dd=0;dd<48;dd++) acc[dd]=0.f;
  for (int i2=0;i2<6;i2++){
    for (int j2=0;j2<jmax;j2++){
      long kr = (long)tl*NDENSE + (wh*6+i2)*64 + ww*6+j2;
      const u16* kp = QKV + kr*QKVLD + 384 + hh*48;
      float s = dot48(qv, kp)*ATT_SCALE;
      attn_upd(s, kp+384, m, l, acc);
    }
  }
  long orow = (long)(t0+tl)*NTOT + NSPARSE + d0;
  store48(O + orow*HIDD + hh*48, acc, 1.f/l);
}

__global__ __launch_bounds__(256) void attn_vr_p1(const u16* __restrict__ Q, const u16* __restrict__ KV,
                                                  float* __restrict__ P, int t0){
  int tl = blockIdx.x, hh = blockIdx.y;
  int w = threadIdx.x>>6, lane = threadIdx.x&63;
  int seg = blockIdx.z*4 + w;
  long qr = (long)(t0+tl)*NVIRT + lane;
  float qv[48]; load48f(Q + qr*HIDD + hh*48, qv);
  float m=-3e38f, l=0.f, acc[48];
#pragma unroll
  for (int d=0;d<48;d++) acc[d]=0.f;
  int k0 = seg*52, k1 = k0+52;
  for (int mk=k0; mk<k1; ++mk){
    long kr = (long)tl*NREAL + mk;
    const u16* kp = KV + kr*768 + hh*48;
    float s = dot48(qv, kp)*ATT_SCALE;
    attn_upd(s, kp+384, m, l, acc);
  }
  float* p = P + ((((long)tl*NHEAD + hh)*16 + seg)*64 + lane)*50;
  p[0]=m; p[1]=l;
#pragma unroll
  for (int d=0;d<48;d++) p[2+d]=acc[d];
}

__global__ __launch_bounds__(64) void attn_vr_p2(const float* __restrict__ P, u16* __restrict__ O, int t0){
  int tl = blockIdx.x, hh = blockIdx.y, lane = threadIdx.x;
  const float* pb = P + (((long)tl*NHEAD + hh)*16*64 + lane)*50;
  float M2 = -3e38f;
#pragma unroll
  for (int sg=0;sg<16;sg++) M2 = fmaxf(M2, pb[(long)sg*64*50 + 0]);
  float L=0.f, out[48];
#pragma unroll
  for (int d=0;d<48;d++) out[d]=0.f;
#pragma unroll
  for (int sg=0;sg<16;sg++){
    const float* pp = pb + (long)sg*64*50;
    float c = __expf(pp[0]-M2);
    L += pp[1]*c;
#pragma unroll
    for (int d=0;d<48;d++) out[d] += pp[2+d]*c;
  }
  long orow = (long)(t0+tl)*NTOT + NREAL + lane;
  store48(O + orow*HIDD + hh*48, out, 1.f/L);
}

__global__ __launch_bounds__(64) void attn_cross_rv(const u16* __restrict__ Q, const u16* __restrict__ KV, u16* __restrict__ O){
  int lane = threadIdx.x;
  int t = blockIdx.y, hh = blockIdx.z;
  int n = blockIdx.x*64 + lane;
  long qr = (long)t*NREAL + n;
  float qv[48]; load48f(Q + qr*HIDD + hh*48, qv);
  float m=-3e38f, l=0.f, acc[48];
#pragma unroll
  for (int d=0;d<48;d++) acc[d]=0.f;
  for (int tk=0;tk<NVIRT;tk++){
    long kr = (long)t*NVIRT + tk;
    const u16* kp = KV + kr*768 + hh*48;
    float s = dot48(qv, kp)*ATT_SCALE;
    attn_upd(s, kp+384, m, l, acc);
  }
  long orow = (long)t*NTOT + n;
  store48(O + orow*HIDD + hh*48, acc, 1.f/l);
}

// ---------------- host ----------------
static const size_t LW_SAQKV = 0;
static const size_t LW_SAO   = LW_SAQKV + 3ul*442368;
static const size_t LW_SAF1  = LW_SAO   + 3ul*147456;
static const size_t LW_SAF2  = LW_SAF1  + 3ul*589824;
static const size_t LW_CAQ   = LW_SAF2  + 3ul*589824;
static const size_t LW_CAKV  = LW_CAQ   + 2ul*147456;
static const size_t LW_CAO   = LW_CAKV  + 2ul*294912;
static const size_t LW_CAF1  = LW_CAO   + 2ul*147456;
static const size_t LW_CAF2  = LW_CAF1  + 2ul*589824;
static const size_t LW_TOTAL = LW_CAF2  + 2ul*589824;

static const size_t QKV_ELEMS = (size_t)MIDCAP*FFD;      // 41,680,896
static const size_t VRKV_OFF  = 1048576;
static const size_t VRP_OFFB  = 44040192;
static const size_t RVKV_OFF  = 21000000;

extern "C" void kernel_launch(void* const* d_in, const int* in_sizes, int n_in,
                              void* d_out, int out_size, void* d_ws, size_t ws_size,
                              hipStream_t stream)
{
  const float* in_t   = (const float*)d_in[0];
  const float* w_in   = (const float*)d_in[2];
  const float* b_in   = (const float*)d_in[3];
  const float* w_out  = (const float*)d_in[4];
  const float* b_out  = (const float*)d_in[5];
  const float* vtr    = (const float*)d_in[6];
  const float* sa_qw  = (const float*)d_in[7];
  const float* sa_qb  = (const float*)d_in[8];
  const float* sa_kvw = (const float*)d_in[9];
  const float* sa_kvb = (const float*)d_in[10];
  const float* sa_ow  = (const float*)d_in[11];
  const float* sa_ob  = (const float*)d_in[12];
  const float* sa_f1w = (const float*)d_in[13];
  const float* sa_f1b = (const float*)d_in[14];
  const float* sa_f2w = (const float*)d_in[15];
  const float* sa_f2b = (const float*)d_in[16];
  const float* ca_qw  = (const float*)d_in[17];
  const float* ca_qb  = (const float*)d_in[18];
  const float* ca_kvw = (const float*)d_in[19];
  const float* ca_kvb = (const float*)d_in[20];
  const float* ca_ow  = (const float*)d_in[21];
  const float* ca_ob  = (const float*)d_in[22];
  const float* ca_f1w = (const float*)d_in[23];
  const float* ca_f1b = (const float*)d_in[24];
  const float* ca_f2w = (const float*)d_in[25];
  const float* ca_f2b = (const float*)d_in[26];
  const float* ca_ncw = (const float*)d_in[27];
  const float* ca_ncb = (const float*)d_in[28];

  char* ws = (char*)d_ws;
  size_t off = 0;
  auto alloc = [&](size_t bytes)->void*{
    void* p = ws + off;
    off += (bytes + 255) & ~(size_t)255;
    return p;
  };
  float* x   = (float*)alloc((size_t)ROWS_ALL*HIDD*4);
  u16* h     = (u16*)alloc((size_t)ROWS_ALL*HIDD*2);      // always current LN(x)
  u16* qkv   = (u16*)alloc(QKV_ELEMS*2);
  u16* wt    = (u16*)alloc(LW_TOTAL*2);
  float* fb  = (float*)alloc(6ul*3*1152*4);
  float* cb  = (float*)alloc(12ul*768*4);
  u16* mid   = qkv;
  u16* inb   = qkv;
  u16* vrQ   = qkv;
  u16* vrKV  = qkv + VRKV_OFF;
  float* vrP = (float*)((char*)qkv + VRP_OFFB);
  u16* rvQ   = qkv;
  u16* rvKV  = qkv + RVKV_OFF;

  // mode 0=bf16, 1=bf16+gelu, 2=f32, 3=f32+res
  auto gemm = [&](int mode, const u16* A, int ldA, int aBase, int aRofs, int aSeg, int aStr,
                  const u16* Bt, const float* bias,
                  void* C, int ldC, int cBase, int cRofs, int cSeg, int cStr,
                  int M, int Nn, int Npad, int K){
    if (Npad == 384){
      dim3 g(M/64, 1), b(512);
      if (mode==0)      gemm_mfma64<0,0,0,0,6><<<g,b,0,stream>>>(A,ldA,aBase,aRofs,aSeg,aStr,Bt,bias,C,ldC,cBase,cRofs,cSeg,cStr,Nn,K,nullptr,0.f);
      else if (mode==1) gemm_mfma64<0,0,1,0,6><<<g,b,0,stream>>>(A,ldA,aBase,aRofs,aSeg,aStr,Bt,bias,C,ldC,cBase,cRofs,cSeg,cStr,Nn,K,nullptr,0.f);
      else if (mode==2) gemm_mfma64<1,0,0,0,6><<<g,b,0,stream>>>(A,ldA,aBase,aRofs,aSeg,aStr,Bt,bias,C,ldC,cBase,cRofs,cSeg,cStr,Nn,K,nullptr,0.f);
      else              gemm_mfma64<1,1,0,0,6><<<g,b,0,stream>>>(A,ldA,aBase,aRofs,aSeg,aStr,Bt,bias,C,ldC,cBase,cRofs,cSeg,cStr,Nn,K,nullptr,0.f);
    } else if (Npad == 256){
      dim3 g(M/64, 1), b(512);
      gemm_mfma64<1,0,0,0,4><<<g,b,0,stream>>>(A,ldA,aBase,aRofs,aSeg,aStr,Bt,bias,C,ldC,cBase,cRofs,cSeg,cStr,Nn,K,nullptr,0.f);
    } else {
      dim3 g(M/128, Npad/384), b(512);
      if (mode==0)      gemm_mfma<0,0,0,12><<<g,b,0,stream>>>(A,ldA,aBase,aRofs,aSeg,aStr,Bt,bias,C,ldC,cBase,cRofs,cSeg,cStr,Nn,K);
      else if (mode==1) gemm_mfma<0,0,1,12><<<g,b,0,stream>>>(A,ldA,aBase,aRofs,aSeg,aStr,Bt,bias,C,ldC,cBase,cRofs,cSeg,cStr,Nn,K);
      else if (mode==2) gemm_mfma<1,0,0,12><<<g,b,0,stream>>>(A,ldA,aBase,aRofs,aSeg,aStr,Bt,bias,C,ldC,cBase,cRofs,cSeg,cStr,Nn,K);
      else              gemm_mfma<1,1,0,12><<<g,b,0,stream>>>(A,ldA,aBase,aRofs,aSeg,aStr,Bt,bias,C,ldC,cBase,cRofs,cSeg,cStr,Nn,K);
    }
  };
  auto gemmLN = [&](const u16* A, int ldA, int aBase, int aRofs, int aSeg, int aStr,
                    const u16* Bt, const float* bias,
                    float* C, int ldC, int cBase, int cRofs, int cSeg, int cStr,
                    int M, int K){
    dim3 g(M/64, 1), b(512);
    gemm_mfma64<1,1,0,1,6><<<g,b,0,stream>>>(A,ldA,aBase,aRofs,aSeg,aStr,Bt,bias,C,ldC,cBase,cRofs,cSeg,cStr,384,K,h,1e-6f);
  };
  auto mlp = [&](int M, int base, int seg, int str,
                 const u16* f1t, const float* f1bias, const u16* f2t, const float* f2bias){
    for (int r0=0; r0<M; r0+=MIDCAP){
      int Mc = (M-r0 < MIDCAP) ? (M-r0) : MIDCAP;
      gemm(1, h, HIDD, base, r0, seg, str, f1t, f1bias, mid, FFD, 0, 0, IDSEG, 0, Mc, FFD, FFD, HIDD);
      gemmLN(mid, FFD, 0, 0, IDSEG, 0, f2t, f2bias, x, HIDD, base, r0, seg, str, Mc, FFD);
    }
  };

  // ---- input projection + token assembly ----
  {
    transpose_cast<<<dim3(10,12,1), dim3(32,8), 0, stream>>>(w_in, wt, 320, 384, 384);
    pack_bias<<<dim3(6), dim3(512), 0, stream>>>(sa_qb, sa_kvb, fb);
    kv_bias_all<<<dim3(2,6), dim3(768), 0, stream>>>(ca_kvw, ca_kvb, ca_ncb, cb);
    long nin = (long)T_STEPS*NREAL*320;
    cast_arr<<<dim3((unsigned)((nin+255)/256)), dim3(256), 0, stream>>>(in_t, inb, nin);
    set_virt<<<dim3((T_STEPS*NVIRT*HIDD+255)/256), dim3(256), 0, stream>>>(vtr, x);
    gemm(2, inb, 320, 0,0,IDSEG,0, wt, b_in, x, HIDD, 0,0,NREAL,NTOT, T_STEPS*NREAL, 384, 384, 320);
    ln_rows<<<dim3((ROWS_ALL+3)/4), dim3(256), 0, stream>>>(x, h, ROWS_ALL);
  }

  // ---- 6 layers ----
  for (int j=0; j<6; ++j){
    TPack tp;
    auto setd = [&](int i, const float* src, long sS, u16* dst, long dS,
                    const float* scale, long scS, int K, int N, int Npad, int nmat){
      tp.d[i] = TDesc{src, sS, dst, dS, scale, scS, K, N, Npad, nmat};
    };
    setd(0, sa_qw  + (size_t)j*147456, 6l*147456, wt+LW_SAQKV,        442368, nullptr, 0, 384, 384,  384,  3);
    setd(1, sa_kvw + (size_t)j*294912, 6l*294912, wt+LW_SAQKV+147456, 442368, nullptr, 0, 384, 768,  768,  3);
    setd(2, sa_ow  + (size_t)j*147456, 6l*147456, wt+LW_SAO,  147456, nullptr, 0, 384, 384,  384,  3);
    setd(3, sa_f1w + (size_t)j*589824, 6l*589824, wt+LW_SAF1, 589824, nullptr, 0, 384, 1536, 1536, 3);
    setd(4, sa_f2w + (size_t)j*589824, 6l*589824, wt+LW_SAF2, 589824, nullptr, 0, 1536,384,  384,  3);
    setd(5, ca_qw  + (size_t)j*147456, 6l*147456, wt+LW_CAQ,  147456, nullptr, 0, 384, 384,  384,  2);
    setd(6, ca_kvw + (size_t)j*294912, 6l*294912, wt+LW_CAKV, 294912, ca_ncw + (size_t)j*384, 6l*384, 384, 768, 768, 2);
    setd(7, ca_ow  + (size_t)j*147456, 6l*147456, wt+LW_CAO,  147456, nullptr, 0, 384, 384,  384,  2);
    setd(8, ca_f1w + (size_t)j*589824, 6l*589824, wt+LW_CAF1, 589824, nullptr, 0, 384, 1536, 1536, 2);
    setd(9, ca_f2w + (size_t)j*589824, 6l*589824, wt+LW_CAF2, 589824, nullptr, 0, 1536,384,  384,  2);
    int zs = 0;
    for (int i=0;i<10;i++){ tp.zo[i] = zs; zs += tp.d[i].nmat; }
    tp.zo[10] = zs;
    transpose_pack<<<dim3(48,48,25), dim3(32,8), 0, stream>>>(tp);
    const float* fbL = fb + (size_t)j*3*1152;
    const float* cbL = cb + (size_t)j*2*768;

    // ===== self over time: h = LN(x) for all rows =====
    {
      int sl = 0*6 + j;
      for (int g2=0; g2<2; ++g2){
        int n0 = g2*NG;
        gemm(0, h, HIDD, n0,0,NG,NTOT, wt+LW_SAQKV, fbL, qkv, QKVLD, 0,0,IDSEG,0, T_STEPS*NG, QKVLD, QKVLD, 384);
        attn_time_g<<<dim3(NG/4, NHEAD), 64, 0, stream>>>(qkv, h, n0);
      }
      gemmLN(h, HIDD, 0,0,IDSEG,0, wt+LW_SAO, sa_ob+sl*384, x, HIDD, 0,0,IDSEG,0, ROWS_ALL, 384);
      mlp(ROWS_ALL, 0, IDSEG, 0, wt+LW_SAF1, sa_f1b+sl*1536, wt+LW_SAF2, sa_f2b+sl*384);
    }

    // ===== cross: virt queries <- real context (ctx LN folded into KV weights) =====
    {
      int cl = 0*6 + j;
      gemm(0, h, HIDD, NREAL,0,NVIRT,NTOT, wt+LW_CAQ, ca_qb+cl*384, vrQ, HIDD, 0,0,IDSEG,0, T_STEPS*NVIRT, 384,384,384);
      for (int tc=0; tc<T_STEPS; tc+=8){
        gemm(0, h, HIDD, tc*NTOT,0,NREAL,NTOT, wt+LW_CAKV, cbL, vrKV, 768, 0,0,IDSEG,0, 8*NREAL, 768,768,384);
        attn_vr_p1<<<dim3(8, NHEAD, 4), 256, 0, stream>>>(vrQ, vrKV, vrP, tc);
        attn_vr_p2<<<dim3(8, NHEAD),     64, 0, stream>>>(vrP, h, tc);
      }
      gemmLN(h, HIDD, NREAL,0,NVIRT,NTOT, wt+LW_CAO, ca_ob+cl*384, x, HIDD, NREAL,0,NVIRT,NTOT, T_STEPS*NVIRT, 384);
      mlp(T_STEPS*NVIRT, NREAL, NVIRT, NTOT, wt+LW_CAF1, ca_f1b+cl*1536, wt+LW_CAF2, ca_f2b+cl*384);
    }

    // ===== self over virt tokens =====
    {
      int sl = 1*6 + j;
      gemm(0, h, HIDD, NREAL,0,NVIRT,NTOT, wt+LW_SAQKV+1ul*442368, fbL+1152, qkv, QKVLD, 0,0,IDSEG,0, T_STEPS*NVIRT, QKVLD, QKVLD, 384);
      attn_virt<<<dim3(T_STEPS, NHEAD), 64, 0, stream>>>(qkv, h);
      gemmLN(h, HIDD, NREAL,0,NVIRT,NTOT, wt+LW_SAO+1ul*147456, sa_ob+sl*384, x, HIDD, NREAL,0,NVIRT,NTOT, T_STEPS*NVIRT, 384);
      mlp(T_STEPS*NVIRT, NREAL, NVIRT, NTOT, wt+LW_SAF1+1ul*589824, sa_f1b+sl*1536, wt+LW_SAF2+1ul*589824, sa_f2b+sl*384);
    }

    // ===== local windowed self over dense tokens =====
    {
      int sl = 2*6 + j;
      for (int tc=0; tc<T_STEPS; tc+=8){
        gemm(0, h, HIDD, tc*NTOT+NSPARSE,0,NDENSE,NTOT, wt+LW_SAQKV+2ul*442368, fbL+2304, qkv, QKVLD, 0,0,IDSEG,0, 8*NDENSE, QKVLD, QKVLD, 384);
        attn_local_g<<<dim3(88, 8, NHEAD), 64, 0, stream>>>(qkv, h, tc);
      }
      gemmLN(h, HIDD, NSPARSE,0,NDENSE,NTOT, wt+LW_SAO+2ul*147456, sa_ob+sl*384, x, HIDD, NSPARSE,0,NDENSE,NTOT, T_STEPS*NDENSE, 384);
      mlp(T_STEPS*NDENSE, NSPARSE, NDENSE, NTOT, wt+LW_SAF1+2ul*589824, sa_f1b+sl*1536, wt+LW_SAF2+2ul*589824, sa_f2b+sl*384);
    }

    // ===== cross: real queries <- virt context (ctx LN folded into KV weights) =====
    {
      int cl = 1*6 + j;
      gemm(0, h, HIDD, NREAL,0,NVIRT,NTOT, wt+LW_CAKV+1ul*294912, cbL+768, rvKV, 768, 0,0,IDSEG,0, T_STEPS*NVIRT, 768,768,384);
      gemm(0, h, HIDD, 0,0,NREAL,NTOT, wt+LW_CAQ+1ul*147456, ca_qb+cl*384, rvQ, HIDD, 0,0,IDSEG,0, T_STEPS*NREAL, 384,384,384);
      attn_cross_rv<<<dim3(52, T_STEPS, NHEAD), 64, 0, stream>>>(rvQ, rvKV, h);
      gemmLN(h, HIDD, 0,0,NREAL,NTOT, wt+LW_CAO+1ul*147456, ca_ob+cl*384, x, HIDD, 0,0,NREAL,NTOT, T_STEPS*NREAL, 384);
      mlp(T_STEPS*NREAL, 0, NREAL, NTOT, wt+LW_CAF1+1ul*589824, ca_f1b+cl*1536, wt+LW_CAF2+1ul*589824, ca_f2b+cl*384);
    }
  }

  // ---- output projection ----
  transpose_cast<<<dim3(12,8,1), dim3(32,8), 0, stream>>>(w_out, wt, 384, 130, 256);
  cast_rows<<<dim3((T_STEPS*NREAL+3)/4), dim3(256), 0, stream>>>(x, h, T_STEPS*NREAL, 0, NREAL, NTOT);
  gemm(2, h, HIDD, 0,0,NREAL,NTOT, wt, b_out, d_out, 130, 0,0,IDSEG,0, T_STEPS*NREAL, 130, 256, 384);
}